// Round 2
// baseline (182.993 us; speedup 1.0000x reference)
//
#include <hip/hip_runtime.h>

// Problem constants
#define B_  2
#define L_  128
#define D_  256
#define H_  8
#define R_  4
#define DK_ 32
#define BL_ (B_*L_)

// Kernel 1: per row (b,l): LayerNorm(q) -> qn; pk = k@Wk, pv = v@Wv, pq = qn@Wq;
//           qkdot[row,h] = sum_d pq[row,h,d]*pk[row,h,d]  (pq/pk not materialized)
__global__ __launch_bounds__(256) void k_proj(
    const float* __restrict__ q, const float* __restrict__ k, const float* __restrict__ v,
    const float* __restrict__ Wq, const float* __restrict__ Wk, const float* __restrict__ Wv,
    const float* __restrict__ ln_g, const float* __restrict__ ln_b,
    float* __restrict__ pv, float* __restrict__ qkdot)
{
    const int row = blockIdx.x;      // b*L + l
    const int tid = threadIdx.x;     // 0..255 (column)
    __shared__ float sqn[D_], sk[D_], sv[D_], red[D_];

    float qv = q[row*D_ + tid];
    sk[tid] = k[row*D_ + tid];
    sv[tid] = v[row*D_ + tid];

    // mean
    red[tid] = qv;
    __syncthreads();
    for (int off = 128; off >= 1; off >>= 1) {
        if (tid < off) red[tid] += red[tid + off];
        __syncthreads();
    }
    float mu = red[0] * (1.0f / D_);
    __syncthreads();
    // variance (ddof=0)
    float dq = qv - mu;
    red[tid] = dq * dq;
    __syncthreads();
    for (int off = 128; off >= 1; off >>= 1) {
        if (tid < off) red[tid] += red[tid + off];
        __syncthreads();
    }
    float var = red[0] * (1.0f / D_);
    float qn = dq * rsqrtf(var + 1e-6f) * ln_g[tid] + ln_b[tid];
    __syncthreads();                 // red[0] reads done before red reused below
    sqn[tid] = qn;
    __syncthreads();

    // three GEMVs: column tid of each projection
    float aq = 0.f, ak = 0.f, av = 0.f;
    for (int dd = 0; dd < D_; ++dd) {
        aq += sqn[dd] * Wq[dd*D_ + tid];
        ak += sk[dd]  * Wk[dd*D_ + tid];
        av += sv[dd]  * Wv[dd*D_ + tid];
    }
    pv[row*D_ + tid] = av;

    red[tid] = aq * ak;
    __syncthreads();
    if (tid < H_) {
        float sdot = 0.f;
        for (int d2 = 0; d2 < DK_; ++d2) sdot += red[tid*DK_ + d2];
        qkdot[row*H_ + tid] = sdot;
    }
}

// Kernel 2: per (b,i): phi kernels, logits+softmax (all 8 heads), attn @ (Phi*pv),
//           then fc + bias + residual. Writes both outputs (out, attn).
__global__ __launch_bounds__(256) void k_attn_out(
    const float* __restrict__ q, const float* __restrict__ t, const float* __restrict__ omega,
    const float* __restrict__ s, const float* __restrict__ fc_w, const float* __restrict__ fc_b,
    const float* __restrict__ pv, const float* __restrict__ qkdot,
    float* __restrict__ dout)
{
    const int bi = blockIdx.x;
    const int b = bi >> 7;
    const int i = bi & (L_-1);
    const int tid = threadIdx.x;

    __shared__ float sPhi[L_], sPsi[L_], sAttn[H_][L_], sMid[D_], sRed[256];
    __shared__ float sS[R_];
    if (tid < R_) sS[tid] = s[tid];
    __syncthreads();

    const float t_i = t[b*L_ + i];
    if (tid < L_) {
        float dtv = fabsf(t_i - t[b*L_ + tid]);
        float Phi = 0.f, Psi = 0.f;
        for (int r = 0; r < R_; ++r) {
            float e = expf(-dtv * sS[r]);
            Phi += e;        // sum_r exp(-dt*s_r)
            Psi += e * e;    // sum_r exp(-2*dt*s_r)
        }
        sPhi[tid] = Phi;
        sPsi[tid] = Psi;
    }
    __syncthreads();

    const float invtemp = 0.17677669529663687f;  // 1/sqrt(32)
    const int j    = tid & (L_-1);
    const int half = tid >> 7;                   // 2 heads per pass
    const float om = omega[(b*L_ + i)*L_ + j];

    for (int hh = 0; hh < H_; hh += 2) {
        const int h = hh + half;
        float logit = (j <= i)
            ? om * sPsi[j] * qkdot[(b*L_ + j)*H_ + h] * invtemp
            : -1e9f;
        // max over the 128-thread half
        sRed[tid] = logit; __syncthreads();
        for (int off = 64; off >= 1; off >>= 1) {
            if ((tid & 127) < off) sRed[tid] = fmaxf(sRed[tid], sRed[tid + off]);
            __syncthreads();
        }
        float mx = sRed[half << 7];
        __syncthreads();
        float e = (j <= i) ? expf(logit - mx) : 0.f;
        // sum
        sRed[tid] = e; __syncthreads();
        for (int off = 64; off >= 1; off >>= 1) {
            if ((tid & 127) < off) sRed[tid] += sRed[tid + off];
            __syncthreads();
        }
        float denom = sRed[half << 7];
        __syncthreads();
        float a = e / denom;
        sAttn[h][j] = a;
        dout[BL_*D_ + ((b*H_ + h)*L_ + i)*L_ + j] = a;
    }
    __syncthreads();

    // out_mid[b,i,h*DK+d] = sum_j attn[h][j] * Phi[j] * pv[b,j,h*DK+d]
    const int h3 = tid >> 5;   // tid = h*32 + d
    float acc = 0.f;
    for (int jj = 0; jj <= i; ++jj)   // attn == 0 for jj > i
        acc += sAttn[h3][jj] * sPhi[jj] * pv[(b*L_ + jj)*D_ + tid];
    sMid[tid] = acc;
    __syncthreads();

    // final: out_mid @ fc_w + fc_b + residual(q)
    float r = fc_b[tid] + q[(b*L_ + i)*D_ + tid];
    for (int kk = 0; kk < D_; ++kk)
        r += sMid[kk] * fc_w[kk*D_ + tid];
    dout[(b*L_ + i)*D_ + tid] = r;
}

extern "C" void kernel_launch(void* const* d_in, const int* in_sizes, int n_in,
                              void* d_out, int out_size, void* d_ws, size_t ws_size,
                              hipStream_t stream) {
    const float* q     = (const float*)d_in[0];
    const float* k     = (const float*)d_in[1];
    const float* v     = (const float*)d_in[2];
    const float* t     = (const float*)d_in[3];
    const float* omega = (const float*)d_in[4];
    // d_in[5] = mask (bool) — causal triu(1), hardcoded as j<=i, not read
    const float* Wq    = (const float*)d_in[6];
    const float* Wk    = (const float*)d_in[7];
    const float* Wv    = (const float*)d_in[8];
    const float* s     = (const float*)d_in[9];
    const float* fc_w  = (const float*)d_in[10];
    const float* fc_b  = (const float*)d_in[11];
    const float* ln_g  = (const float*)d_in[12];
    const float* ln_b  = (const float*)d_in[13];

    float* ws    = (float*)d_ws;
    float* pv    = ws;               // BL*D   = 65536 floats
    float* qkdot = ws + 65536;       // BL*H   = 2048 floats  (total ~270 KB)
    float* out   = (float*)d_out;    // [0,65536): out (B,L,D); [65536,327680): attn (B,H,L,L)

    hipLaunchKernelGGL(k_proj, dim3(BL_), dim3(256), 0, stream,
                       q, k, v, Wq, Wk, Wv, ln_g, ln_b, pv, qkdot);
    hipLaunchKernelGGL(k_attn_out, dim3(BL_), dim3(256), 0, stream,
                       q, t, omega, s, fc_w, fc_b, pv, qkdot, out);
}

// Round 3
// 136.788 us; speedup vs baseline: 1.3378x; 1.3378x over previous
//
#include <hip/hip_runtime.h>

// Problem constants
#define B_  2
#define L_  128
#define D_  256
#define H_  8
#define R_  4
#define DK_ 32
#define BL_ (B_*L_)

__device__ __forceinline__ float wredsum64(float v) {
    #pragma unroll
    for (int m = 32; m >= 1; m >>= 1) v += __shfl_xor(v, m, 64);
    return v;
}
__device__ __forceinline__ float wredmax64(float v) {
    #pragma unroll
    for (int m = 32; m >= 1; m >>= 1) v = fmaxf(v, __shfl_xor(v, m, 64));
    return v;
}

// Kernel 1: per row (b,l): LayerNorm(q); pq=qn@Wq, pk=k@Wk, pv=v@Wv (float4,
// K split over the 4 waves); qkdot[row,h] = sum_d pq[h,d]*pk[h,d].
__global__ __launch_bounds__(256) void k_proj(
    const float* __restrict__ q, const float* __restrict__ k, const float* __restrict__ v,
    const float* __restrict__ Wq, const float* __restrict__ Wk, const float* __restrict__ Wv,
    const float* __restrict__ ln_g, const float* __restrict__ ln_b,
    float* __restrict__ pv, float* __restrict__ qkdot)
{
    const int row = blockIdx.x;
    const int tid = threadIdx.x;
    __shared__ __align__(16) float sx[3][D_];      // qn, k, v
    __shared__ __align__(16) float part[4][3][D_]; // K-quarter partials
    __shared__ float red[8];

    // stage q,k,v row via float4
    if (tid < 192) {
        const int which = tid >> 6, c4 = tid & 63;
        const float* src = (which == 0) ? q : (which == 1) ? k : v;
        reinterpret_cast<float4*>(sx[which])[c4] =
            reinterpret_cast<const float4*>(src + (size_t)row * D_)[c4];
    }
    __syncthreads();

    // LayerNorm stats (sum, sumsq) via wave shuffles + 4-wave LDS combine
    {
        float qv = sx[0][tid];
        float s1 = qv, s2 = qv * qv;
        #pragma unroll
        for (int m = 32; m >= 1; m >>= 1) {
            s1 += __shfl_xor(s1, m, 64);
            s2 += __shfl_xor(s2, m, 64);
        }
        if ((tid & 63) == 0) { red[(tid >> 6) * 2] = s1; red[(tid >> 6) * 2 + 1] = s2; }
    }
    __syncthreads();
    {
        float mu  = (red[0] + red[2] + red[4] + red[6]) * (1.0f / D_);
        float msq = (red[1] + red[3] + red[5] + red[7]) * (1.0f / D_);
        float var = msq - mu * mu;
        float qn = (sx[0][tid] - mu) * rsqrtf(var + 1e-6f) * ln_g[tid] + ln_b[tid];
        sx[0][tid] = qn;   // each thread rewrites only its own slot
    }
    __syncthreads();

    // GEMV: wave kq handles K rows [kq*64, kq*64+64); lane c4 handles cols 4c4..4c4+3
    const int kq = tid >> 6, c4 = tid & 63;
    const float4* Wq4 = reinterpret_cast<const float4*>(Wq);
    const float4* Wk4 = reinterpret_cast<const float4*>(Wk);
    const float4* Wv4 = reinterpret_cast<const float4*>(Wv);
    float4 aq = {0,0,0,0}, ak = {0,0,0,0}, av = {0,0,0,0};
    const int base = kq * 64;
    #pragma unroll 8
    for (int dd = 0; dd < 64; ++dd) {
        const int r = base + dd;
        const float xq = sx[0][r], xk = sx[1][r], xv = sx[2][r];
        const float4 wq = Wq4[r * 64 + c4];
        const float4 wk = Wk4[r * 64 + c4];
        const float4 wv = Wv4[r * 64 + c4];
        aq.x += xq * wq.x; aq.y += xq * wq.y; aq.z += xq * wq.z; aq.w += xq * wq.w;
        ak.x += xk * wk.x; ak.y += xk * wk.y; ak.z += xk * wk.z; ak.w += xk * wk.w;
        av.x += xv * wv.x; av.y += xv * wv.y; av.z += xv * wv.z; av.w += xv * wv.w;
    }
    reinterpret_cast<float4*>(part[kq][0])[c4] = aq;
    reinterpret_cast<float4*>(part[kq][1])[c4] = ak;
    reinterpret_cast<float4*>(part[kq][2])[c4] = av;
    __syncthreads();

    // combine partials; col = tid
    const float pq  = part[0][0][tid] + part[1][0][tid] + part[2][0][tid] + part[3][0][tid];
    const float pk  = part[0][1][tid] + part[1][1][tid] + part[2][1][tid] + part[3][1][tid];
    const float pvv = part[0][2][tid] + part[1][2][tid] + part[2][2][tid] + part[3][2][tid];
    pv[(size_t)row * D_ + tid] = pvv;

    // qkdot per head: reduce pq*pk within each 32-lane (head) group
    float d = pq * pk;
    #pragma unroll
    for (int m = 16; m >= 1; m >>= 1) d += __shfl_xor(d, m, 64);
    if ((tid & 31) == 0) qkdot[(size_t)row * H_ + (tid >> 5)] = d;
}

// Kernel 2: per (b,i): Phi/Psi, per-head softmax (wave-shuffle), attn@(Phi*pv),
// fc + bias + residual. Writes both outputs (out, attn).
__global__ __launch_bounds__(256) void k_attn_out(
    const float* __restrict__ q, const float* __restrict__ t, const float* __restrict__ omega,
    const float* __restrict__ s, const float* __restrict__ fc_w, const float* __restrict__ fc_b,
    const float* __restrict__ pv, const float* __restrict__ qkdot,
    float* __restrict__ dout)
{
    const int bi = blockIdx.x;
    const int b = bi >> 7;
    const int i = bi & (L_ - 1);
    const int tid = threadIdx.x;

    __shared__ __align__(16) float sQK[L_ * H_];   // [j][h]
    __shared__ __align__(16) float sAttn[H_][L_];
    __shared__ __align__(16) float sMid[D_];
    __shared__ __align__(16) float part[4][D_];
    __shared__ float sPhi[L_], sPsi[L_], sOm[L_];
    __shared__ float sS[R_];

    if (tid < R_) sS[tid] = s[tid];
    // stage this batch's qkdot block (128x8 floats) via float4
    reinterpret_cast<float4*>(sQK)[tid] =
        reinterpret_cast<const float4*>(qkdot + (size_t)b * L_ * H_)[tid];
    if (tid < L_) sOm[tid] = omega[((size_t)(b * L_ + i)) * L_ + tid];
    __syncthreads();

    if (tid < L_) {
        const float dtv = fabsf(t[b * L_ + i] - t[b * L_ + tid]);
        float Phi = 0.f, Psi = 0.f;
        #pragma unroll
        for (int r = 0; r < R_; ++r) {
            const float e = expf(-dtv * sS[r]);
            Phi += e;        // sum_r exp(-dt*s_r)
            Psi += e * e;    // sum_r exp(-2*dt*s_r)
        }
        sPhi[tid] = Phi;
        sPsi[tid] = Psi;
    }
    __syncthreads();

    // softmax: wave w handles heads w and w+4; lane covers j=lane and j=lane+64
    const int w = tid >> 6, lane = tid & 63;
    const float invtemp = 0.17677669529663687f;  // 1/sqrt(32)
    #pragma unroll
    for (int pass = 0; pass < 2; ++pass) {
        const int h = w + pass * 4;
        const int j0 = lane, j1 = lane + 64;
        float l0 = (j0 <= i) ? sOm[j0] * sPsi[j0] * sQK[j0 * H_ + h] * invtemp : -3.0e38f;
        float l1 = (j1 <= i) ? sOm[j1] * sPsi[j1] * sQK[j1 * H_ + h] * invtemp : -3.0e38f;
        const float mx = wredmax64(fmaxf(l0, l1));
        const float e0 = (j0 <= i) ? expf(l0 - mx) : 0.f;
        const float e1 = (j1 <= i) ? expf(l1 - mx) : 0.f;
        const float inv = 1.0f / wredsum64(e0 + e1);
        const float a0 = e0 * inv, a1 = e1 * inv;
        sAttn[h][j0] = a0;
        sAttn[h][j1] = a1;
        const size_t ab = (size_t)BL_ * D_ + (((size_t)(b * H_ + h) * L_ + i) * L_);
        dout[ab + j0] = a0;
        dout[ab + j1] = a1;
    }
    __syncthreads();

    // mid[col] = sum_j attn[h(col)][j] * Phi[j] * pv[b,j,col]; j split over 4 waves
    const int jq = tid >> 6, c4 = tid & 63;
    const int h3 = c4 >> 3;                       // head of cols 4c4..4c4+3
    const float4* pv4 = reinterpret_cast<const float4*>(pv + (size_t)b * L_ * D_);
    float4 acc = {0,0,0,0};
    #pragma unroll 4
    for (int jj = jq; jj <= i; jj += 4) {
        const float wgt = sAttn[h3][jj] * sPhi[jj];
        const float4 pvv = pv4[jj * 64 + c4];
        acc.x += wgt * pvv.x; acc.y += wgt * pvv.y; acc.z += wgt * pvv.z; acc.w += wgt * pvv.w;
    }
    reinterpret_cast<float4*>(part[jq])[c4] = acc;
    __syncthreads();
    sMid[tid] = part[0][tid] + part[1][tid] + part[2][tid] + part[3][tid];
    __syncthreads();

    // fc: out[col] = sum_k mid[k]*fc_w[k,col]; K split over 4 waves
    const float4* fw4 = reinterpret_cast<const float4*>(fc_w);
    float4 r4 = {0,0,0,0};
    const int basek = jq * 64;
    #pragma unroll 8
    for (int kk = 0; kk < 64; ++kk) {
        const int kr = basek + kk;
        const float xm = sMid[kr];
        const float4 fw = fw4[kr * 64 + c4];
        r4.x += xm * fw.x; r4.y += xm * fw.y; r4.z += xm * fw.z; r4.w += xm * fw.w;
    }
    reinterpret_cast<float4*>(part[jq])[c4] = r4;
    __syncthreads();

    const size_t orow = (size_t)(b * L_ + i) * D_;
    const float r = part[0][tid] + part[1][tid] + part[2][tid] + part[3][tid]
                  + fc_b[tid] + q[orow + tid];
    dout[orow + tid] = r;
}

extern "C" void kernel_launch(void* const* d_in, const int* in_sizes, int n_in,
                              void* d_out, int out_size, void* d_ws, size_t ws_size,
                              hipStream_t stream) {
    const float* q     = (const float*)d_in[0];
    const float* k     = (const float*)d_in[1];
    const float* v     = (const float*)d_in[2];
    const float* t     = (const float*)d_in[3];
    const float* omega = (const float*)d_in[4];
    // d_in[5] = mask (bool) — causal triu(1), hardcoded as j<=i, not read
    const float* Wq    = (const float*)d_in[6];
    const float* Wk    = (const float*)d_in[7];
    const float* Wv    = (const float*)d_in[8];
    const float* s     = (const float*)d_in[9];
    const float* fc_w  = (const float*)d_in[10];
    const float* fc_b  = (const float*)d_in[11];
    const float* ln_g  = (const float*)d_in[12];
    const float* ln_b  = (const float*)d_in[13];

    float* ws    = (float*)d_ws;
    float* pv    = ws;               // BL*D = 65536 floats
    float* qkdot = ws + 65536;       // BL*H = 2048 floats
    float* out   = (float*)d_out;    // [0,65536): out (B,L,D); [65536,327680): attn (B,H,L,L)

    hipLaunchKernelGGL(k_proj, dim3(BL_), dim3(256), 0, stream,
                       q, k, v, Wq, Wk, Wv, ln_g, ln_b, pv, qkdot);
    hipLaunchKernelGGL(k_attn_out, dim3(BL_), dim3(256), 0, stream,
                       q, t, omega, s, fc_w, fc_b, pv, qkdot, out);
}

// Round 4
// 99.966 us; speedup vs baseline: 1.8306x; 1.3683x over previous
//
#include <hip/hip_runtime.h>

// Problem constants
#define B_  2
#define L_  128
#define D_  256
#define H_  8
#define R_  4
#define DK_ 32
#define BL_ (B_*L_)

__device__ __forceinline__ float wredsum64(float v) {
    #pragma unroll
    for (int m = 32; m >= 1; m >>= 1) v += __shfl_xor(v, m, 64);
    return v;
}
__device__ __forceinline__ float wredmax64(float v) {
    #pragma unroll
    for (int m = 32; m >= 1; m >>= 1) v = fmaxf(v, __shfl_xor(v, m, 64));
    return v;
}

// K1: grid 1024 = 256 rows x 4 colgroups(64 cols). Per block: LN(q) (redundant
// across the 4 cg, cheap), 3 GEMVs for its 64 cols with 16-way K split,
// pv -> ws, qkdot for its 2 heads -> ws.
__global__ __launch_bounds__(256) void k_proj(
    const float* __restrict__ q, const float* __restrict__ k, const float* __restrict__ v,
    const float* __restrict__ Wq, const float* __restrict__ Wk, const float* __restrict__ Wv,
    const float* __restrict__ ln_g, const float* __restrict__ ln_b,
    float* __restrict__ pv, float* __restrict__ qkdot)
{
    const int blk = blockIdx.x;
    const int row = blk >> 2;                 // b*L + l
    const int cg  = blk & 3;                  // column group
    const int tid = threadIdx.x;

    __shared__ __align__(16) float sx[3][D_];        // qn, k, v rows
    __shared__ __align__(16) float part[16][3][64];  // K-group partials
    __shared__ float red[8];
    __shared__ float spq[64], spk[64];

    // stage q,k,v rows (float4)
    if (tid < 192) {
        const int which = tid >> 6, f4 = tid & 63;
        const float* src = (which == 0) ? q : (which == 1) ? k : v;
        reinterpret_cast<float4*>(sx[which])[f4] =
            reinterpret_cast<const float4*>(src + (size_t)row * D_)[f4];
    }
    __syncthreads();

    // LayerNorm stats via wave shuffles + 4-wave combine
    {
        const float qv = sx[0][tid];
        float s1 = qv, s2 = qv * qv;
        #pragma unroll
        for (int m = 32; m >= 1; m >>= 1) {
            s1 += __shfl_xor(s1, m, 64);
            s2 += __shfl_xor(s2, m, 64);
        }
        if ((tid & 63) == 0) { red[(tid >> 6) * 2] = s1; red[(tid >> 6) * 2 + 1] = s2; }
    }
    __syncthreads();
    {
        const float mu  = (red[0] + red[2] + red[4] + red[6]) * (1.0f / D_);
        const float msq = (red[1] + red[3] + red[5] + red[7]) * (1.0f / D_);
        const float var = msq - mu * mu;
        const float qn = (sx[0][tid] - mu) * rsqrtf(var + 1e-6f) * ln_g[tid] + ln_b[tid];
        __syncthreads();               // everyone read sx[0] before overwrite
        sx[0][tid] = qn;
    }
    __syncthreads();

    // GEMV: thread = (kg, c4); 16 K-values x 1 float4-col per matrix
    const int c4  = tid & 15;                 // local float4 col
    const int kg  = tid >> 4;                 // K group
    const int gc4 = cg * 16 + c4;             // global float4 col
    const int kbase = kg * 16;
    {
        const float4* W4 = reinterpret_cast<const float4*>(Wq);
        float4 a = {0,0,0,0};
        #pragma unroll
        for (int kk = 0; kk < 16; ++kk) {
            const int r = kbase + kk;
            const float x = sx[0][r];
            const float4 w = W4[r * 64 + gc4];
            a.x += x * w.x; a.y += x * w.y; a.z += x * w.z; a.w += x * w.w;
        }
        reinterpret_cast<float4*>(part[kg][0])[c4] = a;
    }
    {
        const float4* W4 = reinterpret_cast<const float4*>(Wk);
        float4 a = {0,0,0,0};
        #pragma unroll
        for (int kk = 0; kk < 16; ++kk) {
            const int r = kbase + kk;
            const float x = sx[1][r];
            const float4 w = W4[r * 64 + gc4];
            a.x += x * w.x; a.y += x * w.y; a.z += x * w.z; a.w += x * w.w;
        }
        reinterpret_cast<float4*>(part[kg][1])[c4] = a;
    }
    {
        const float4* W4 = reinterpret_cast<const float4*>(Wv);
        float4 a = {0,0,0,0};
        #pragma unroll
        for (int kk = 0; kk < 16; ++kk) {
            const int r = kbase + kk;
            const float x = sx[2][r];
            const float4 w = W4[r * 64 + gc4];
            a.x += x * w.x; a.y += x * w.y; a.z += x * w.z; a.w += x * w.w;
        }
        reinterpret_cast<float4*>(part[kg][2])[c4] = a;
    }
    __syncthreads();

    // combine 16 K-partials; m=0 -> spq, m=1 -> spk, m=2 -> pv (global)
    if (tid < 192) {
        const int m = tid >> 6, c = tid & 63;
        float sum = 0.f;
        #pragma unroll
        for (int g = 0; g < 16; ++g) sum += part[g][m][c];
        if      (m == 0) spq[c] = sum;
        else if (m == 1) spk[c] = sum;
        else             pv[(size_t)row * D_ + cg * 64 + c] = sum;
    }
    __syncthreads();

    // qkdot for this block's 2 heads
    if (tid < 64) {
        float d = spq[tid] * spk[tid];
        #pragma unroll
        for (int m = 16; m >= 1; m >>= 1) d += __shfl_xor(d, m, 64);
        if ((tid & 31) == 0)
            qkdot[(size_t)row * H_ + cg * 2 + (tid >> 5)] = d;
    }
}

// K2: grid 1024 = (b,i) x 4 cg. Per block: Phi/Psi, softmax for its 2 heads
// (writes attn to dout), mid for its 64 cols -> ws.
__global__ __launch_bounds__(256) void k_attn(
    const float* __restrict__ t, const float* __restrict__ omega, const float* __restrict__ s,
    const float* __restrict__ pv, const float* __restrict__ qkdot,
    float* __restrict__ mid, float* __restrict__ dout)
{
    const int blk = blockIdx.x;
    const int b  = blk >> 9;
    const int i  = (blk >> 2) & (L_ - 1);
    const int cg = blk & 3;
    const int tid = threadIdx.x;

    __shared__ __align__(16) float sQK[L_ * H_];     // [j][h]
    __shared__ __align__(16) float sOm[L_];
    __shared__ __align__(16) float sAttn[2][L_];
    __shared__ __align__(16) float part[16][64];
    __shared__ float sPhi[L_], sPsi[L_], sS[R_];

    if (tid < R_) sS[tid] = s[tid];
    reinterpret_cast<float4*>(sQK)[tid] =
        reinterpret_cast<const float4*>(qkdot + (size_t)b * L_ * H_)[tid];
    if (tid < 32)
        reinterpret_cast<float4*>(sOm)[tid] =
            reinterpret_cast<const float4*>(omega + ((size_t)(b * L_ + i)) * L_)[tid];
    __syncthreads();

    if (tid < L_) {
        const float dtv = fabsf(t[b * L_ + i] - t[b * L_ + tid]);
        float Phi = 0.f, Psi = 0.f;
        #pragma unroll
        for (int r = 0; r < R_; ++r) {
            const float e = expf(-dtv * sS[r]);
            Phi += e;
            Psi += e * e;
        }
        sPhi[tid] = Phi;
        sPsi[tid] = Psi;
    }
    __syncthreads();

    // softmax: waves 0,1 handle the block's 2 heads
    const int w = tid >> 6, lane = tid & 63;
    const float invtemp = 0.17677669529663687f;  // 1/sqrt(32)
    if (w < 2) {
        const int h = cg * 2 + w;
        const int j0 = lane, j1 = lane + 64;
        float l0 = (j0 <= i) ? sOm[j0] * sPsi[j0] * sQK[j0 * H_ + h] * invtemp : -3.0e38f;
        float l1 = (j1 <= i) ? sOm[j1] * sPsi[j1] * sQK[j1 * H_ + h] * invtemp : -3.0e38f;
        const float mx = wredmax64(fmaxf(l0, l1));
        const float e0 = (j0 <= i) ? expf(l0 - mx) : 0.f;
        const float e1 = (j1 <= i) ? expf(l1 - mx) : 0.f;
        const float inv = 1.0f / wredsum64(e0 + e1);
        const float a0 = e0 * inv, a1 = e1 * inv;
        sAttn[w][j0] = a0;
        sAttn[w][j1] = a1;
        const size_t ab = (size_t)BL_ * D_ + (((size_t)(b * H_ + h) * L_ + i) * L_);
        dout[ab + j0] = a0;
        dout[ab + j1] = a1;
    }
    __syncthreads();

    // mid[col] = sum_j attn[h(col)][j] * Phi[j] * pv[b,j,col], 16-way j split
    const int c4  = tid & 15;
    const int jg  = tid >> 4;
    const int gc4 = cg * 16 + c4;
    const int hl  = (gc4 >> 3) & 1;           // local head of cols 4*gc4..
    const float4* pv4 = reinterpret_cast<const float4*>(pv + (size_t)b * L_ * D_);
    float4 acc = {0,0,0,0};
    for (int j = jg; j <= i; j += 16) {
        const float wgt = sAttn[hl][j] * sPhi[j];
        const float4 p = pv4[j * 64 + gc4];
        acc.x += wgt * p.x; acc.y += wgt * p.y; acc.z += wgt * p.z; acc.w += wgt * p.w;
    }
    reinterpret_cast<float4*>(part[jg])[c4] = acc;
    __syncthreads();
    if (tid < 64) {
        float sum = 0.f;
        #pragma unroll
        for (int g = 0; g < 16; ++g) sum += part[g][tid];
        mid[((size_t)(b * L_ + i)) * D_ + cg * 64 + tid] = sum;
    }
}

// K3: grid 1024 = 256 rows x 4 cg. out = mid @ fc_w + fc_b + residual(q).
__global__ __launch_bounds__(256) void k_fc(
    const float* __restrict__ q, const float* __restrict__ fc_w, const float* __restrict__ fc_b,
    const float* __restrict__ mid, float* __restrict__ dout)
{
    const int blk = blockIdx.x;
    const int row = blk >> 2;
    const int cg  = blk & 3;
    const int tid = threadIdx.x;

    __shared__ __align__(16) float sMid[D_];
    __shared__ __align__(16) float part[16][64];

    if (tid < 64)
        reinterpret_cast<float4*>(sMid)[tid] =
            reinterpret_cast<const float4*>(mid + (size_t)row * D_)[tid];
    __syncthreads();

    const int c4  = tid & 15;
    const int kg  = tid >> 4;
    const int gc4 = cg * 16 + c4;
    const int kbase = kg * 16;
    const float4* fw4 = reinterpret_cast<const float4*>(fc_w);
    float4 a = {0,0,0,0};
    #pragma unroll
    for (int kk = 0; kk < 16; ++kk) {
        const int r = kbase + kk;
        const float x = sMid[r];
        const float4 w = fw4[r * 64 + gc4];
        a.x += x * w.x; a.y += x * w.y; a.z += x * w.z; a.w += x * w.w;
    }
    reinterpret_cast<float4*>(part[kg])[c4] = a;
    __syncthreads();

    if (tid < 64) {
        const int c = cg * 64 + tid;
        float sum = fc_b[c] + q[(size_t)row * D_ + c];
        #pragma unroll
        for (int g = 0; g < 16; ++g) sum += part[g][tid];
        dout[(size_t)row * D_ + c] = sum;
    }
}

extern "C" void kernel_launch(void* const* d_in, const int* in_sizes, int n_in,
                              void* d_out, int out_size, void* d_ws, size_t ws_size,
                              hipStream_t stream) {
    const float* q     = (const float*)d_in[0];
    const float* k     = (const float*)d_in[1];
    const float* v     = (const float*)d_in[2];
    const float* t     = (const float*)d_in[3];
    const float* omega = (const float*)d_in[4];
    // d_in[5] = mask (bool) — causal triu(1), hardcoded as j<=i, not read
    const float* Wq    = (const float*)d_in[6];
    const float* Wk    = (const float*)d_in[7];
    const float* Wv    = (const float*)d_in[8];
    const float* s     = (const float*)d_in[9];
    const float* fc_w  = (const float*)d_in[10];
    const float* fc_b  = (const float*)d_in[11];
    const float* ln_g  = (const float*)d_in[12];
    const float* ln_b  = (const float*)d_in[13];

    float* ws    = (float*)d_ws;
    float* pv    = ws;               // BL*D = 65536 floats
    float* qkdot = ws + 65536;       // BL*H = 2048 floats
    float* mid   = ws + 67584;       // BL*D = 65536 floats  (total ~532 KB)
    float* out   = (float*)d_out;    // [0,65536): out (B,L,D); [65536,327680): attn (B,H,L,L)

    hipLaunchKernelGGL(k_proj, dim3(4 * BL_), dim3(256), 0, stream,
                       q, k, v, Wq, Wk, Wv, ln_g, ln_b, pv, qkdot);
    hipLaunchKernelGGL(k_attn, dim3(4 * BL_), dim3(256), 0, stream,
                       t, omega, s, pv, qkdot, mid, out);
    hipLaunchKernelGGL(k_fc, dim3(4 * BL_), dim3(256), 0, stream,
                       q, fc_w, fc_b, mid, out);
}

// Round 5
// 98.101 us; speedup vs baseline: 1.8653x; 1.0190x over previous
//
#include <hip/hip_runtime.h>

// Problem constants
#define B_  2
#define L_  128
#define D_  256
#define H_  8
#define R_  4
#define DK_ 32
#define BL_ (B_*L_)
// 8 column-groups of 32 cols (== one head) per block; grid = 8*BL_ = 2048

__device__ __forceinline__ float wredsum64(float v) {
    #pragma unroll
    for (int m = 32; m >= 1; m >>= 1) v += __shfl_xor(v, m, 64);
    return v;
}
__device__ __forceinline__ float wredmax64(float v) {
    #pragma unroll
    for (int m = 32; m >= 1; m >>= 1) v = fmaxf(v, __shfl_xor(v, m, 64));
    return v;
}

// K1: grid 2048 = 256 rows x 8 cg(32 cols = 1 head). LN(q) (redundant per cg,
// cheap), 3 GEMVs for 32 cols with 32-way K split, pv -> ws, qkdot[row, cg] -> ws.
__global__ __launch_bounds__(256) void k_proj(
    const float* __restrict__ q, const float* __restrict__ k, const float* __restrict__ v,
    const float* __restrict__ Wq, const float* __restrict__ Wk, const float* __restrict__ Wv,
    const float* __restrict__ ln_g, const float* __restrict__ ln_b,
    float* __restrict__ pv, float* __restrict__ qkdot)
{
    const int blk = blockIdx.x;
    const int row = blk >> 3;                 // b*L + l
    const int cg  = blk & 7;                  // column group == head
    const int tid = threadIdx.x;

    __shared__ __align__(16) float sx[3][D_];        // qn, k, v rows (3 KB)
    __shared__ __align__(16) float part[32][3][32];  // K-group partials (12 KB)
    __shared__ float red[8];
    __shared__ float spq[32], spk[32];

    // stage q,k,v rows (float4)
    if (tid < 192) {
        const int which = tid >> 6, f4 = tid & 63;
        const float* src = (which == 0) ? q : (which == 1) ? k : v;
        reinterpret_cast<float4*>(sx[which])[f4] =
            reinterpret_cast<const float4*>(src + (size_t)row * D_)[f4];
    }
    __syncthreads();

    // LayerNorm stats via wave shuffles + 4-wave combine
    {
        const float qv = sx[0][tid];
        float s1 = qv, s2 = qv * qv;
        #pragma unroll
        for (int m = 32; m >= 1; m >>= 1) {
            s1 += __shfl_xor(s1, m, 64);
            s2 += __shfl_xor(s2, m, 64);
        }
        if ((tid & 63) == 0) { red[(tid >> 6) * 2] = s1; red[(tid >> 6) * 2 + 1] = s2; }
    }
    __syncthreads();
    {
        const float mu  = (red[0] + red[2] + red[4] + red[6]) * (1.0f / D_);
        const float msq = (red[1] + red[3] + red[5] + red[7]) * (1.0f / D_);
        const float var = msq - mu * mu;
        const float qn = (sx[0][tid] - mu) * rsqrtf(var + 1e-6f) * ln_g[tid] + ln_b[tid];
        __syncthreads();               // everyone read sx[0] before overwrite
        sx[0][tid] = qn;
    }
    __syncthreads();

    // GEMV: thread = (kg 0..31, c4 0..7); 8 K-rows x 1 float4-col per matrix
    const int kg  = tid >> 3;
    const int c4  = tid & 7;
    const int gc4 = cg * 8 + c4;              // global float4 col
    const int kbase = kg * 8;
    {
        const float4* W4 = reinterpret_cast<const float4*>(Wq);
        float4 a = {0,0,0,0};
        #pragma unroll
        for (int kk = 0; kk < 8; ++kk) {
            const float x = sx[0][kbase + kk];
            const float4 w = W4[(kbase + kk) * 64 + gc4];
            a.x += x * w.x; a.y += x * w.y; a.z += x * w.z; a.w += x * w.w;
        }
        reinterpret_cast<float4*>(part[kg][0])[c4] = a;
    }
    {
        const float4* W4 = reinterpret_cast<const float4*>(Wk);
        float4 a = {0,0,0,0};
        #pragma unroll
        for (int kk = 0; kk < 8; ++kk) {
            const float x = sx[1][kbase + kk];
            const float4 w = W4[(kbase + kk) * 64 + gc4];
            a.x += x * w.x; a.y += x * w.y; a.z += x * w.z; a.w += x * w.w;
        }
        reinterpret_cast<float4*>(part[kg][1])[c4] = a;
    }
    {
        const float4* W4 = reinterpret_cast<const float4*>(Wv);
        float4 a = {0,0,0,0};
        #pragma unroll
        for (int kk = 0; kk < 8; ++kk) {
            const float x = sx[2][kbase + kk];
            const float4 w = W4[(kbase + kk) * 64 + gc4];
            a.x += x * w.x; a.y += x * w.y; a.z += x * w.z; a.w += x * w.w;
        }
        reinterpret_cast<float4*>(part[kg][2])[c4] = a;
    }
    __syncthreads();

    // combine 32 K-partials; m=0 -> spq, m=1 -> spk, m=2 -> pv (global)
    if (tid < 96) {
        const int m = tid >> 5, c = tid & 31;
        float sum = 0.f;
        #pragma unroll
        for (int g = 0; g < 32; ++g) sum += part[g][m][c];
        if      (m == 0) spq[c] = sum;
        else if (m == 1) spk[c] = sum;
        else             pv[(size_t)row * D_ + cg * 32 + c] = sum;
    }
    __syncthreads();

    // qkdot for this block's head (cols 32cg..32cg+31 are exactly head cg)
    if (tid < 32) {
        float d = spq[tid] * spk[tid];
        #pragma unroll
        for (int m = 16; m >= 1; m >>= 1) d += __shfl_xor(d, m, 64);
        if (tid == 0) qkdot[(size_t)row * H_ + cg] = d;
    }
}

// K2: grid 2048 = (b,i) x 8 heads. Phi/Psi, softmax for head h (writes attn to
// dout), mid for its 32 cols -> ws.
__global__ __launch_bounds__(256) void k_attn(
    const float* __restrict__ t, const float* __restrict__ omega, const float* __restrict__ s,
    const float* __restrict__ pv, const float* __restrict__ qkdot,
    float* __restrict__ mid, float* __restrict__ dout)
{
    const int blk = blockIdx.x;
    const int b  = blk >> 10;
    const int i  = (blk >> 3) & (L_ - 1);
    const int h  = blk & 7;
    const int tid = threadIdx.x;

    __shared__ __align__(16) float sQK[L_ * H_];     // [j][h]  (4 KB)
    __shared__ __align__(16) float sOm[L_];
    __shared__ __align__(16) float sAttn[L_];
    __shared__ __align__(16) float part[32][32];     // (4 KB)
    __shared__ float sPhi[L_], sPsi[L_], sS[R_];

    if (tid < R_) sS[tid] = s[tid];
    reinterpret_cast<float4*>(sQK)[tid] =
        reinterpret_cast<const float4*>(qkdot + (size_t)b * L_ * H_)[tid];
    if (tid < 32)
        reinterpret_cast<float4*>(sOm)[tid] =
            reinterpret_cast<const float4*>(omega + ((size_t)(b * L_ + i)) * L_)[tid];
    __syncthreads();

    if (tid < L_) {
        const float dtv = fabsf(t[b * L_ + i] - t[b * L_ + tid]);
        float Phi = 0.f, Psi = 0.f;
        #pragma unroll
        for (int r = 0; r < R_; ++r) {
            const float e = expf(-dtv * sS[r]);
            Phi += e;
            Psi += e * e;
        }
        sPhi[tid] = Phi;
        sPsi[tid] = Psi;
    }
    __syncthreads();

    // softmax for head h on wave 0 (each lane covers j and j+64)
    const float invtemp = 0.17677669529663687f;  // 1/sqrt(32)
    if (tid < 64) {
        const int j0 = tid, j1 = tid + 64;
        float l0 = (j0 <= i) ? sOm[j0] * sPsi[j0] * sQK[j0 * H_ + h] * invtemp : -3.0e38f;
        float l1 = (j1 <= i) ? sOm[j1] * sPsi[j1] * sQK[j1 * H_ + h] * invtemp : -3.0e38f;
        const float mx = wredmax64(fmaxf(l0, l1));
        const float e0 = (j0 <= i) ? expf(l0 - mx) : 0.f;
        const float e1 = (j1 <= i) ? expf(l1 - mx) : 0.f;
        const float inv = 1.0f / wredsum64(e0 + e1);
        const float a0 = e0 * inv, a1 = e1 * inv;
        sAttn[j0] = a0;
        sAttn[j1] = a1;
        const size_t ab = (size_t)BL_ * D_ + (((size_t)(b * H_ + h) * L_ + i) * L_);
        dout[ab + j0] = a0;
        dout[ab + j1] = a1;
    }
    __syncthreads();

    // mid[col] = sum_j attn[j] * Phi[j] * pv[b,j,col] over the head's 32 cols,
    // 32-way j split (<=4 float4 loads per thread)
    const int jg  = tid >> 3;
    const int c4  = tid & 7;
    const int gc4 = h * 8 + c4;
    const float4* pv4 = reinterpret_cast<const float4*>(pv + (size_t)b * L_ * D_);
    float4 acc = {0,0,0,0};
    for (int j = jg; j <= i; j += 32) {
        const float wgt = sAttn[j] * sPhi[j];
        const float4 p = pv4[j * 64 + gc4];
        acc.x += wgt * p.x; acc.y += wgt * p.y; acc.z += wgt * p.z; acc.w += wgt * p.w;
    }
    reinterpret_cast<float4*>(part[jg])[c4] = acc;
    __syncthreads();
    if (tid < 32) {
        float sum = 0.f;
        #pragma unroll
        for (int g = 0; g < 32; ++g) sum += part[g][tid];
        mid[((size_t)(b * L_ + i)) * D_ + h * 32 + tid] = sum;
    }
}

// K3: grid 2048 = 256 rows x 8 cg. out = mid @ fc_w + fc_b + residual(q).
__global__ __launch_bounds__(256) void k_fc(
    const float* __restrict__ q, const float* __restrict__ fc_w, const float* __restrict__ fc_b,
    const float* __restrict__ mid, float* __restrict__ dout)
{
    const int blk = blockIdx.x;
    const int row = blk >> 3;
    const int cg  = blk & 7;
    const int tid = threadIdx.x;

    __shared__ __align__(16) float sMid[D_];
    __shared__ __align__(16) float part[32][32];

    if (tid < 64)
        reinterpret_cast<float4*>(sMid)[tid] =
            reinterpret_cast<const float4*>(mid + (size_t)row * D_)[tid];
    __syncthreads();

    const int kg  = tid >> 3;
    const int c4  = tid & 7;
    const int gc4 = cg * 8 + c4;
    const int kbase = kg * 8;
    const float4* fw4 = reinterpret_cast<const float4*>(fc_w);
    float4 a = {0,0,0,0};
    #pragma unroll
    for (int kk = 0; kk < 8; ++kk) {
        const float x = sMid[kbase + kk];
        const float4 w = fw4[(kbase + kk) * 64 + gc4];
        a.x += x * w.x; a.y += x * w.y; a.z += x * w.z; a.w += x * w.w;
    }
    reinterpret_cast<float4*>(part[kg])[c4] = a;
    __syncthreads();

    if (tid < 32) {
        const int c = cg * 32 + tid;
        float sum = fc_b[c] + q[(size_t)row * D_ + c];
        #pragma unroll
        for (int g = 0; g < 32; ++g) sum += part[g][tid];
        dout[(size_t)row * D_ + c] = sum;
    }
}

extern "C" void kernel_launch(void* const* d_in, const int* in_sizes, int n_in,
                              void* d_out, int out_size, void* d_ws, size_t ws_size,
                              hipStream_t stream) {
    const float* q     = (const float*)d_in[0];
    const float* k     = (const float*)d_in[1];
    const float* v     = (const float*)d_in[2];
    const float* t     = (const float*)d_in[3];
    const float* omega = (const float*)d_in[4];
    // d_in[5] = mask (bool) — causal triu(1), hardcoded as j<=i, not read
    const float* Wq    = (const float*)d_in[6];
    const float* Wk    = (const float*)d_in[7];
    const float* Wv    = (const float*)d_in[8];
    const float* s     = (const float*)d_in[9];
    const float* fc_w  = (const float*)d_in[10];
    const float* fc_b  = (const float*)d_in[11];
    const float* ln_g  = (const float*)d_in[12];
    const float* ln_b  = (const float*)d_in[13];

    float* ws    = (float*)d_ws;
    float* pv    = ws;               // BL*D = 65536 floats
    float* qkdot = ws + 65536;       // BL*H = 2048 floats
    float* mid   = ws + 67584;       // BL*D = 65536 floats  (total ~532 KB)
    float* out   = (float*)d_out;    // [0,65536): out (B,L,D); [65536,327680): attn (B,H,L,L)

    hipLaunchKernelGGL(k_proj, dim3(8 * BL_), dim3(256), 0, stream,
                       q, k, v, Wq, Wk, Wv, ln_g, ln_b, pv, qkdot);
    hipLaunchKernelGGL(k_attn, dim3(8 * BL_), dim3(256), 0, stream,
                       t, omega, s, pv, qkdot, mid, out);
    hipLaunchKernelGGL(k_fc, dim3(8 * BL_), dim3(256), 0, stream,
                       q, fc_w, fc_b, mid, out);
}

// Round 6
// 95.712 us; speedup vs baseline: 1.9119x; 1.0250x over previous
//
#include <hip/hip_runtime.h>

// Problem constants
#define B_  2
#define L_  128
#define D_  256
#define H_  8
#define R_  4
#define DK_ 32
#define BL_ (B_*L_)
#define SXP 260   // padded row stride (floats) for LDS row arrays (bank decorrelation, 16B-aligned)

__device__ __forceinline__ float wredsum64(float v) {
    #pragma unroll
    for (int m = 32; m >= 1; m >>= 1) v += __shfl_xor(v, m, 64);
    return v;
}
__device__ __forceinline__ float wredmax64(float v) {
    #pragma unroll
    for (int m = 32; m >= 1; m >>= 1) v = fmaxf(v, __shfl_xor(v, m, 64));
    return v;
}

// K1: grid 1024 = 64 rowTiles(4 rows) x 16 cg(16 cols). LN on 4 rows, then 3 GEMVs
// for 16 cols x 4 rows — each weight line serves 4 rows. qk half-head partial
// dots -> qkpart[row][16]; pv -> ws.
__global__ __launch_bounds__(256) void k_proj(
    const float* __restrict__ q, const float* __restrict__ k, const float* __restrict__ v,
    const float* __restrict__ Wq, const float* __restrict__ Wk, const float* __restrict__ Wv,
    const float* __restrict__ ln_g, const float* __restrict__ ln_b,
    float* __restrict__ pv, float* __restrict__ qkpart)
{
    const int blk = blockIdx.x;
    const int rowTile = blk >> 4;
    const int cg = blk & 15;                 // 16 cols per block
    const int rbase = rowTile * 4;
    const int tid = threadIdx.x;

    __shared__ __align__(16) float sx[3][4 * SXP];   // qn,k,v x 4 rows (12.5 KB)
    __shared__ __align__(16) float partF[16 * 4 * 16]; // [kg][row][col16] (4 KB)
    __shared__ float spq[4][16], spk[4][16];

    // stage q,k,v: thread -> (r = tid>>6, f4c = tid&63), loop over the 3 tensors
    {
        const int r = tid >> 6, f4c = tid & 63;
        #pragma unroll
        for (int p = 0; p < 3; ++p) {
            const float* src = (p == 0 ? q : (p == 1 ? k : v)) + (size_t)(rbase + r) * D_;
            *reinterpret_cast<float4*>(&sx[p][r * SXP + f4c * 4]) =
                reinterpret_cast<const float4*>(src)[f4c];
        }
    }
    __syncthreads();

    // LayerNorm: wave w owns row w; lane covers cols lane+64j. Shuffle-reduce
    // leaves the totals in every lane — no LDS broadcast needed.
    {
        const int r = tid >> 6, lane = tid & 63;
        float x0 = sx[0][r * SXP + lane];
        float x1 = sx[0][r * SXP + lane + 64];
        float x2 = sx[0][r * SXP + lane + 128];
        float x3 = sx[0][r * SXP + lane + 192];
        float s1 = x0 + x1 + x2 + x3;
        float s2 = x0*x0 + x1*x1 + x2*x2 + x3*x3;
        #pragma unroll
        for (int m = 32; m >= 1; m >>= 1) {
            s1 += __shfl_xor(s1, m, 64);
            s2 += __shfl_xor(s2, m, 64);
        }
        const float mu = s1 * (1.0f / D_);
        const float rs = rsqrtf(s2 * (1.0f / D_) - mu * mu + 1e-6f);
        sx[0][r * SXP + lane      ] = (x0 - mu) * rs * ln_g[lane      ] + ln_b[lane      ];
        sx[0][r * SXP + lane +  64] = (x1 - mu) * rs * ln_g[lane +  64] + ln_b[lane +  64];
        sx[0][r * SXP + lane + 128] = (x2 - mu) * rs * ln_g[lane + 128] + ln_b[lane + 128];
        sx[0][r * SXP + lane + 192] = (x3 - mu) * rs * ln_g[lane + 192] + ln_b[lane + 192];
    }
    __syncthreads();

    // GEMV: thread = (kg 0..15, row 0..3, c4 0..3); 16 K-steps; the 4 row-threads
    // of a (kg,c4) share every weight float4 (same address -> one line).
    const int kg  = tid >> 4;
    const int row = (tid >> 2) & 3;
    const int c4  = tid & 3;
    const int gc4 = cg * 4 + c4;             // global float4 col (0..63)
    const int kbase = kg * 16;

    #pragma unroll
    for (int m = 0; m < 3; ++m) {
        const float4* W4 = reinterpret_cast<const float4*>(m == 0 ? Wq : (m == 1 ? Wk : Wv));
        float4 a = {0, 0, 0, 0};
        #pragma unroll
        for (int kk = 0; kk < 16; ++kk) {
            const int kr = kbase + kk;
            const float x = sx[m][row * SXP + kr];
            const float4 w = W4[kr * 64 + gc4];
            a.x += x * w.x; a.y += x * w.y; a.z += x * w.z; a.w += x * w.w;
        }
        *reinterpret_cast<float4*>(&partF[(kg * 16 + row * 4 + c4) * 4]) = a;
        __syncthreads();
        if (tid < 64) {                      // reduce over kg: float idx kg*64 + rr*16 + cc
            const int rr = tid >> 4, cc = tid & 15;
            float sum = 0.f;
            #pragma unroll
            for (int g = 0; g < 16; ++g) sum += partF[g * 64 + rr * 16 + cc];
            if      (m == 0) spq[rr][cc] = sum;
            else if (m == 1) spk[rr][cc] = sum;
            else             pv[(size_t)(rbase + rr) * D_ + cg * 16 + cc] = sum;
        }
        __syncthreads();
    }

    // half-head partial dot: reduce spq*spk over the block's 16 cols
    if (tid < 64) {
        const int rr = tid >> 4, cc = tid & 15;
        float d = spq[rr][cc] * spk[rr][cc];
        #pragma unroll
        for (int m = 8; m >= 1; m >>= 1) d += __shfl_xor(d, m, 64);
        if (cc == 0) qkpart[(size_t)(rbase + rr) * 16 + cg] = d;
    }
}

// K2: grid 512 = b x 32 iTiles(4 i per block, one per wave) x 8 heads.
// Phi/Psi per (i_local,j), softmax per wave, mid with pv lines shared by 4 i's.
__global__ __launch_bounds__(256) void k_attn(
    const float* __restrict__ t, const float* __restrict__ omega, const float* __restrict__ s,
    const float* __restrict__ pv, const float* __restrict__ qkpart,
    float* __restrict__ mid, float* __restrict__ dout)
{
    const int blk = blockIdx.x;
    const int b     = blk >> 8;
    const int itile = (blk >> 3) & 31;
    const int h     = blk & 7;
    const int ibase = itile * 4;
    const int tid = threadIdx.x;

    __shared__ __align__(16) float sQKp[L_ * 16];    // staged qk partials (8 KB)
    __shared__ __align__(16) float sQKh[L_];         // combined for this head
    __shared__ __align__(16) float sOm[4 * L_];
    __shared__ __align__(16) float sPhi[4 * L_], sPsi[4 * L_];
    __shared__ __align__(16) float sAttn[4 * L_];
    __shared__ __align__(16) float partF[32 * 4 * 32]; // [jg][w][col32] (16 KB)
    __shared__ float st[L_], sS[R_];

    // staging
    {
        const float4* qkp4 = reinterpret_cast<const float4*>(qkpart + (size_t)b * L_ * 16);
        reinterpret_cast<float4*>(sQKp)[tid]       = qkp4[tid];
        reinterpret_cast<float4*>(sQKp)[tid + 256] = qkp4[tid + 256];
        if (tid < 128)
            reinterpret_cast<float4*>(sOm)[tid] =
                reinterpret_cast<const float4*>(omega + ((size_t)(b * L_ + ibase)) * L_)[tid];
        if (tid < 32)
            reinterpret_cast<float4*>(st)[tid] =
                reinterpret_cast<const float4*>(t + (size_t)b * L_)[tid];
        if (tid < R_) sS[tid] = s[tid];
    }
    __syncthreads();

    // combine the two half-head dots; Phi/Psi for 4 i's x 128 j's
    if (tid < 128) sQKh[tid] = sQKp[tid * 16 + 2 * h] + sQKp[tid * 16 + 2 * h + 1];
    #pragma unroll
    for (int p = 0; p < 2; ++p) {
        const int idx = tid + p * 256;
        const int w = idx >> 7, j = idx & 127;
        const float dtv = fabsf(st[ibase + w] - st[j]);
        float Phi = 0.f, Psi = 0.f;
        #pragma unroll
        for (int r = 0; r < R_; ++r) {
            const float e = expf(-dtv * sS[r]);
            Phi += e;
            Psi += e * e;
        }
        sPhi[idx] = Phi;
        sPsi[idx] = Psi;
    }
    __syncthreads();

    // softmax: wave w -> i = ibase+w (lanes cover j and j+64)
    const int w = tid >> 6, lane = tid & 63;
    const int i = ibase + w;
    {
        const float invtemp = 0.17677669529663687f;  // 1/sqrt(32)
        const int j0 = lane, j1 = lane + 64;
        float l0 = (j0 <= i) ? sOm[w*L_ + j0] * sPsi[w*L_ + j0] * sQKh[j0] * invtemp : -3.0e38f;
        float l1 = (j1 <= i) ? sOm[w*L_ + j1] * sPsi[w*L_ + j1] * sQKh[j1] * invtemp : -3.0e38f;
        const float mx = wredmax64(fmaxf(l0, l1));
        const float e0 = (j0 <= i) ? expf(l0 - mx) : 0.f;
        const float e1 = (j1 <= i) ? expf(l1 - mx) : 0.f;
        const float inv = 1.0f / wredsum64(e0 + e1);
        const float a0 = e0 * inv, a1 = e1 * inv;
        sAttn[w*L_ + j0] = a0;
        sAttn[w*L_ + j1] = a1;
        const size_t ab = (size_t)BL_ * D_ + (((size_t)(b * H_ + h) * L_ + i) * L_);
        dout[ab + j0] = a0;
        dout[ab + j1] = a1;
    }
    __syncthreads();

    // mid for 4 i's: each pv float4 load feeds 4 accumulators
    {
        const int jg = tid >> 3, c4 = tid & 7;
        const int gc4 = h * 8 + c4;
        const float4* pv4 = reinterpret_cast<const float4*>(pv + (size_t)b * L_ * D_);
        float4 acc[4];
        #pragma unroll
        for (int ww = 0; ww < 4; ++ww) acc[ww] = make_float4(0, 0, 0, 0);
        #pragma unroll
        for (int jj = 0; jj < 4; ++jj) {
            const int j = jg + jj * 32;
            const float4 p = pv4[j * 64 + gc4];
            #pragma unroll
            for (int ww = 0; ww < 4; ++ww) {
                const float wgt = sAttn[ww*L_ + j] * sPhi[ww*L_ + j];  // 0 beyond causal
                acc[ww].x += wgt * p.x; acc[ww].y += wgt * p.y;
                acc[ww].z += wgt * p.z; acc[ww].w += wgt * p.w;
            }
        }
        #pragma unroll
        for (int ww = 0; ww < 4; ++ww)
            *reinterpret_cast<float4*>(&partF[(jg * 32 + ww * 8 + c4) * 4]) = acc[ww];
    }
    __syncthreads();
    if (tid < 128) {   // reduce over jg: float idx jg*128 + w*32 + cc
        const int ww = tid >> 5, cc = tid & 31;
        float sum = 0.f;
        #pragma unroll
        for (int g = 0; g < 32; ++g) sum += partF[g * 128 + ww * 32 + cc];
        mid[((size_t)(b * L_ + ibase + ww)) * D_ + h * 32 + cc] = sum;
    }
}

// K3: grid 1024 = 64 rowTiles(4 rows) x 16 cg. out = mid @ fc_w + fc_b + residual(q);
// fc_w lines shared across the 4 rows.
__global__ __launch_bounds__(256) void k_fc(
    const float* __restrict__ q, const float* __restrict__ fc_w, const float* __restrict__ fc_b,
    const float* __restrict__ mid, float* __restrict__ dout)
{
    const int blk = blockIdx.x;
    const int rowTile = blk >> 4;
    const int cg = blk & 15;
    const int rbase = rowTile * 4;
    const int tid = threadIdx.x;

    __shared__ __align__(16) float smid[4 * SXP];
    __shared__ __align__(16) float partF[16 * 4 * 16];

    {
        const int r = tid >> 6, f4c = tid & 63;
        *reinterpret_cast<float4*>(&smid[r * SXP + f4c * 4]) =
            reinterpret_cast<const float4*>(mid + (size_t)(rbase + r) * D_)[f4c];
    }
    __syncthreads();

    const int kg  = tid >> 4;
    const int row = (tid >> 2) & 3;
    const int c4  = tid & 3;
    const int gc4 = cg * 4 + c4;
    const int kbase = kg * 16;
    const float4* fw4 = reinterpret_cast<const float4*>(fc_w);
    float4 a = {0, 0, 0, 0};
    #pragma unroll
    for (int kk = 0; kk < 16; ++kk) {
        const int kr = kbase + kk;
        const float x = smid[row * SXP + kr];
        const float4 wv = fw4[kr * 64 + gc4];
        a.x += x * wv.x; a.y += x * wv.y; a.z += x * wv.z; a.w += x * wv.w;
    }
    *reinterpret_cast<float4*>(&partF[(kg * 16 + row * 4 + c4) * 4]) = a;
    __syncthreads();

    if (tid < 64) {
        const int rr = tid >> 4, cc = tid & 15;
        const int col = cg * 16 + cc;
        float sum = fc_b[col] + q[(size_t)(rbase + rr) * D_ + col];
        #pragma unroll
        for (int g = 0; g < 16; ++g) sum += partF[g * 64 + rr * 16 + cc];
        dout[(size_t)(rbase + rr) * D_ + col] = sum;
    }
}

extern "C" void kernel_launch(void* const* d_in, const int* in_sizes, int n_in,
                              void* d_out, int out_size, void* d_ws, size_t ws_size,
                              hipStream_t stream) {
    const float* q     = (const float*)d_in[0];
    const float* k     = (const float*)d_in[1];
    const float* v     = (const float*)d_in[2];
    const float* t     = (const float*)d_in[3];
    const float* omega = (const float*)d_in[4];
    // d_in[5] = mask (bool) — causal triu(1), hardcoded as j<=i, not read
    const float* Wq    = (const float*)d_in[6];
    const float* Wk    = (const float*)d_in[7];
    const float* Wv    = (const float*)d_in[8];
    const float* s     = (const float*)d_in[9];
    const float* fc_w  = (const float*)d_in[10];
    const float* fc_b  = (const float*)d_in[11];
    const float* ln_g  = (const float*)d_in[12];
    const float* ln_b  = (const float*)d_in[13];

    float* ws     = (float*)d_ws;
    float* pv     = ws;               // BL*D  = 65536 floats
    float* qkpart = ws + 65536;       // BL*16 = 4096 floats
    float* mid    = ws + 69632;       // BL*D  = 65536 floats
    float* out    = (float*)d_out;    // [0,65536): out (B,L,D); [65536,327680): attn (B,H,L,L)

    hipLaunchKernelGGL(k_proj, dim3(1024), dim3(256), 0, stream,
                       q, k, v, Wq, Wk, Wv, ln_g, ln_b, pv, qkpart);
    hipLaunchKernelGGL(k_attn, dim3(512), dim3(256), 0, stream,
                       t, omega, s, pv, qkpart, mid, out);
    hipLaunchKernelGGL(k_fc, dim3(1024), dim3(256), 0, stream,
                       q, fc_w, fc_b, mid, out);
}